// Round 8
// baseline (360.350 us; speedup 1.0000x reference)
//
#include <hip/hip_runtime.h>
#include <climits>

#define CNT_SHIFT 44
#define SUM_MASK  ((1ULL << 44) - 1)
#define NT 8                      // shadow histogram tables
#define ROW_BITS 17
#define ROW_MASK ((1u << ROW_BITS) - 1)
#define EW_SCALE 32767.0f

// ---------------- f32 -> bf16 (round-to-nearest-even) ----------------
__device__ __forceinline__ unsigned short f2bf(float f) {
  unsigned u = __float_as_uint(f);
  u = (u + 0x7fffu + ((u >> 16) & 1u)) >> 16;
  return (unsigned short)u;
}
__device__ __forceinline__ float bf_lo(unsigned d) { return __uint_as_float(d << 16); }
__device__ __forceinline__ float bf_hi(unsigned d) { return __uint_as_float(d & 0xffff0000u); }

// ---------------- async global->LDS 16B (no VGPR round-trip) ----------------
__device__ __forceinline__ void gload16(const float* g, float* l) {
  __builtin_amdgcn_global_load_lds(
      (const __attribute__((address_space(1))) void*)(g),
      (__attribute__((address_space(3))) void*)(l),
      16, 0, 0);
}

// ---------------- zero shadow histograms, seed min/max ----------------
__global__ void k_zero(unsigned long long* __restrict__ packed,
                       int* __restrict__ gctr, int* __restrict__ mm, int n8) {
  int i = blockIdx.x * blockDim.x + threadIdx.x;
  if (i < n8) packed[i] = 0ULL;
  if (i == 0) { *gctr = 0; mm[0] = INT_MAX; mm[1] = INT_MIN; }
}

// ---------------- min/max: block-reduced, 2 atomics per block ----------------
__global__ void k_minmax(const int* __restrict__ ec, int n, int* __restrict__ mm) {
  __shared__ int smin[4], smax[4];
  int i = blockIdx.x * blockDim.x + threadIdx.x;
  int stride = gridDim.x * blockDim.x;
  int vmin = INT_MAX, vmax = INT_MIN;
  for (; i < n; i += stride) {
    int v = ec[i];
    vmin = min(vmin, v);
    vmax = max(vmax, v);
  }
  #pragma unroll
  for (int o = 32; o > 0; o >>= 1) {
    vmin = min(vmin, __shfl_xor(vmin, o));
    vmax = max(vmax, __shfl_xor(vmax, o));
  }
  int wid = threadIdx.x >> 6;
  if ((threadIdx.x & 63) == 0) { smin[wid] = vmin; smax[wid] = vmax; }
  __syncthreads();
  if (threadIdx.x == 0) {
    #pragma unroll
    for (int w = 1; w < 4; ++w) {
      vmin = min(vmin, smin[w]);
      vmax = max(vmax, smax[w]);
    }
    atomicMin(&mm[0], vmin);
    atomicMax(&mm[1], vmax);
  }
}

// ---------------- histogram over 8 shadow tables (8x fewer same-line RMWs) --
__global__ void k_hist(const int* __restrict__ ecol, const int* __restrict__ ec,
                       unsigned long long* __restrict__ packed,
                       int* __restrict__ rank, int nE, int nN) {
  int i = blockIdx.x * blockDim.x + threadIdx.x;
  if (i >= nE) return;
  int t = threadIdx.x & (NT - 1);
  unsigned long long old =
      atomicAdd(&packed[(size_t)t * nN + ecol[i]],
                (1ULL << CNT_SHIFT) | (unsigned long long)(unsigned)ec[i]);
  rank[i] = (int)(old >> CNT_SHIFT) | (t << 27);
}

// ---------------- combine shadows: rowptr scan, dinv, per-table bases -------
__global__ void k_base(const unsigned long long* __restrict__ packed,
                       const int* __restrict__ mm,
                       int* __restrict__ rowptr, int* __restrict__ cntv,
                       float* __restrict__ dinv, int* __restrict__ subbase,
                       int* __restrict__ gctr, int nN) {
  int i = blockIdx.x * blockDim.x + threadIdx.x;
  int lane = threadIdx.x & 63;
  int pre[NT];
  int total = 0;
  unsigned long long sums = 0;
  if (i < nN) {
    #pragma unroll
    for (int t = 0; t < NT; ++t) {
      unsigned long long pk = packed[(size_t)t * nN + i];
      pre[t] = total;
      total += (int)(pk >> CNT_SHIFT);
      sums += (pk & SUM_MASK);
    }
    float mn = (float)mm[0];
    float rcp = 1.0f / (float)(mm[1] - mm[0]);
    float deg = ((float)sums - (float)total * mn) * rcp;
    dinv[i] = rsqrtf(deg + 1.0f);
  }
  int s = total;
  #pragma unroll
  for (int o = 1; o < 64; o <<= 1) {
    int t = __shfl_up(s, o);
    if (lane >= o) s += t;
  }
  int wtot = __shfl(s, 63);
  int base = 0;
  if (lane == 63) base = atomicAdd(gctr, wtot);
  base = __shfl(base, 63);
  int rp = base + s - total;
  if (i < nN) {
    rowptr[i] = rp;
    cntv[i] = total;
    #pragma unroll
    for (int t = 0; t < NT; ++t) subbase[(size_t)t * nN + i] = rp + pre[t];
  }
}

// ---------------- fill CSR, atomic-free: p = subbase[t][c] + rank ----------
// entry = row (17b) | quantized ew (15b)
__global__ void k_fill(const int* __restrict__ erow, const int* __restrict__ ecol,
                       const int* __restrict__ ec, const int* __restrict__ mm,
                       const int* __restrict__ subbase, const int* __restrict__ rank,
                       unsigned* __restrict__ srcw, int nE, int nN) {
  int e = blockIdx.x * blockDim.x + threadIdx.x;
  if (e >= nE) return;
  float mn = (float)mm[0];
  float rcp = 1.0f / (float)(mm[1] - mm[0]);
  float ew = ((float)ec[e] - mn) * rcp;
  unsigned q = __float2uint_rn(ew * EW_SCALE);
  int rk = rank[e];
  int t = (rk >> 27) & (NT - 1);
  int rin = rk & ((1 << 27) - 1);
  int p = subbase[(size_t)t * nN + ecol[e]] + rin;
  srcw[p] = (unsigned)erow[e] | (q << ROW_BITS);
}

// ---------------- GEMM: [n,K]f32 x [K,64]f32 -> [n,64]bf16 -----------------
template<int K>
__global__ __launch_bounds__(256) void k_gemm(const float* __restrict__ A,
                                              const float* __restrict__ W,
                                              unsigned short* __restrict__ outh, int n) {
  constexpr int KSTEPS = K / 32;
  __shared__ float atile[2][128 * 32];
  __shared__ float wtile[2][32 * 64];
  const int tid = threadIdx.x;
  const int wv = tid >> 6;
  const int tr = tid >> 4, tc = tid & 15;
  const int rbase = blockIdx.x * 128;

  auto stageA = [&](int kt, int b) {
    #pragma unroll
    for (int r = 0; r < 4; ++r) {
      int f = r * 256 + tid;
      int row = f >> 3, c4s = f & 7;
      int c4 = c4s ^ (row & 7);
      int gr = rbase + row; if (gr >= n) gr = n - 1;
      const float* g = A + (size_t)gr * K + kt * 32 + c4 * 4;
      float* l = &atile[b][(r * 256 + wv * 64) * 4];
      gload16(g, l);
    }
  };
  auto stageW = [&](int kt, int b) {
    #pragma unroll
    for (int r = 0; r < 2; ++r) {
      int f = r * 256 + tid;
      int krow = f >> 4, c4 = f & 15;
      const float* g = W + (size_t)(kt * 32 + krow) * 64 + c4 * 4;
      float* l = &wtile[b][(r * 256 + wv * 64) * 4];
      gload16(g, l);
    }
  };

  float4 acc[8];
  #pragma unroll
  for (int i = 0; i < 8; ++i) acc[i] = make_float4(0.f, 0.f, 0.f, 0.f);

  stageA(0, 0); stageW(0, 0);
  __syncthreads();
  int cur = 0;
  for (int kt = 0; kt < KSTEPS; ++kt) {
    if (kt + 1 < KSTEPS) { stageA(kt + 1, cur ^ 1); stageW(kt + 1, cur ^ 1); }
    const float* ab = atile[cur];
    const float* wb = wtile[cur];
    #pragma unroll
    for (int k4 = 0; k4 < 8; ++k4) {
      float4 wv0 = *(const float4*)&wb[(k4 * 4 + 0) * 64 + tc * 4];
      float4 wv1 = *(const float4*)&wb[(k4 * 4 + 1) * 64 + tc * 4];
      float4 wv2 = *(const float4*)&wb[(k4 * 4 + 2) * 64 + tc * 4];
      float4 wv3 = *(const float4*)&wb[(k4 * 4 + 3) * 64 + tc * 4];
      #pragma unroll
      for (int i = 0; i < 8; ++i) {
        int row = tr + 16 * i;
        float4 av = *(const float4*)&ab[row * 32 + ((k4 ^ (row & 7)) * 4)];
        acc[i].x = fmaf(av.x, wv0.x, acc[i].x);
        acc[i].y = fmaf(av.x, wv0.y, acc[i].y);
        acc[i].z = fmaf(av.x, wv0.z, acc[i].z);
        acc[i].w = fmaf(av.x, wv0.w, acc[i].w);
        acc[i].x = fmaf(av.y, wv1.x, acc[i].x);
        acc[i].y = fmaf(av.y, wv1.y, acc[i].y);
        acc[i].z = fmaf(av.y, wv1.z, acc[i].z);
        acc[i].w = fmaf(av.y, wv1.w, acc[i].w);
        acc[i].x = fmaf(av.z, wv2.x, acc[i].x);
        acc[i].y = fmaf(av.z, wv2.y, acc[i].y);
        acc[i].z = fmaf(av.z, wv2.z, acc[i].z);
        acc[i].w = fmaf(av.z, wv2.w, acc[i].w);
        acc[i].x = fmaf(av.w, wv3.x, acc[i].x);
        acc[i].y = fmaf(av.w, wv3.y, acc[i].y);
        acc[i].z = fmaf(av.w, wv3.z, acc[i].z);
        acc[i].w = fmaf(av.w, wv3.w, acc[i].w);
      }
    }
    __syncthreads();
    cur ^= 1;
  }
  #pragma unroll
  for (int i = 0; i < 8; ++i) {
    int row = rbase + tr + 16 * i;
    if (row < n) {
      ushort4 o4;
      o4.x = f2bf(acc[i].x); o4.y = f2bf(acc[i].y);
      o4.z = f2bf(acc[i].z); o4.w = f2bf(acc[i].w);
      *(ushort4*)&outh[(size_t)row * 64 + tc * 4] = o4;
    }
  }
}

// ---------------- aggregation: bf16 gathers, 8 rows in flight per wave ------
template<bool FINAL>
__global__ void k_agg(const int* __restrict__ rowptr, const int* __restrict__ cntv,
                      const unsigned* __restrict__ srcw, const float* __restrict__ dinv,
                      const unsigned short* __restrict__ xwh,  // [nN][64] bf16
                      const float* __restrict__ b,
                      float* __restrict__ outp, int nN) {
  int node = blockIdx.x * (blockDim.x >> 6) + (threadIdx.x >> 6);
  if (node >= nN) return;
  int lane = threadIdx.x & 63;
  int grp = lane >> 3, sub = lane & 7;
  float dc = dinv[node];
  const uint4* xw16 = (const uint4*)xwh;
  float acc[8] = {0.f, 0.f, 0.f, 0.f, 0.f, 0.f, 0.f, 0.f};
  int s = rowptr[node];
  int m = cntv[node];
  for (int cb = 0; cb < m; cb += 64) {
    int take = min(64, m - cb);
    int rsrc = 0;
    float nrmv = 0.f;
    if (lane < take) {
      unsigned rw = srcw[s + cb + lane];
      rsrc = rw & ROW_MASK;
      nrmv = dinv[rsrc] * ((float)(rw >> ROW_BITS) * (1.0f / EW_SCALE)) * dc;
    }
    for (int j = 0; j < take; j += 8) {
      int jj = j + grp;                    // <= 63 always
      int r = __shfl(rsrc, jj);
      float nv = __shfl(nrmv, jj);         // 0 for padded jj >= take
      uint4 d = xw16[(size_t)r * 8 + sub];
      acc[0] = fmaf(nv, bf_lo(d.x), acc[0]);
      acc[1] = fmaf(nv, bf_hi(d.x), acc[1]);
      acc[2] = fmaf(nv, bf_lo(d.y), acc[2]);
      acc[3] = fmaf(nv, bf_hi(d.y), acc[3]);
      acc[4] = fmaf(nv, bf_lo(d.z), acc[4]);
      acc[5] = fmaf(nv, bf_hi(d.z), acc[5]);
      acc[6] = fmaf(nv, bf_lo(d.w), acc[6]);
      acc[7] = fmaf(nv, bf_hi(d.w), acc[7]);
    }
  }
  #pragma unroll
  for (int k = 0; k < 8; ++k) acc[k] += __shfl_xor(acc[k], 8);
  #pragma unroll
  for (int k = 0; k < 8; ++k) acc[k] += __shfl_xor(acc[k], 16);
  #pragma unroll
  for (int k = 0; k < 8; ++k) acc[k] += __shfl_xor(acc[k], 32);

  if (lane < 8) {
    uint4 d = xw16[(size_t)node * 8 + sub];     // self row (bf16)
    float sv[8] = {bf_lo(d.x), bf_hi(d.x), bf_lo(d.y), bf_hi(d.y),
                   bf_lo(d.z), bf_hi(d.z), bf_lo(d.w), bf_hi(d.w)};
    float dcc = dc * dc;
    float v[8];
    #pragma unroll
    for (int k = 0; k < 8; ++k) v[k] = acc[k] + dcc * sv[k] + b[sub * 8 + k];
    size_t o0 = (size_t)node * 64 + sub * 8;
    if (FINAL) {
      *(float4*)&outp[o0]     = make_float4(v[0], v[1], v[2], v[3]);
      *(float4*)&outp[o0 + 4] = make_float4(v[4], v[5], v[6], v[7]);
      float mx = v[0];
      #pragma unroll
      for (int k = 1; k < 8; ++k) mx = fmaxf(mx, v[k]);
      #pragma unroll
      for (int o = 1; o < 8; o <<= 1) mx = fmaxf(mx, __shfl_xor(mx, o));
      float e = 0.f;
      #pragma unroll
      for (int k = 0; k < 8; ++k) e += expf(v[k] - mx);
      #pragma unroll
      for (int o = 1; o < 8; o <<= 1) e += __shfl_xor(e, o);
      float ls = mx + logf(e);
      size_t o1 = (size_t)nN * 64 + o0;
      *(float4*)&outp[o1]     = make_float4(v[0] - ls, v[1] - ls, v[2] - ls, v[3] - ls);
      *(float4*)&outp[o1 + 4] = make_float4(v[4] - ls, v[5] - ls, v[6] - ls, v[7] - ls);
    } else {
      #pragma unroll
      for (int k = 0; k < 8; ++k) v[k] = fmaxf(v[k], 0.f);
      *(float4*)&outp[o0]     = make_float4(v[0], v[1], v[2], v[3]);
      *(float4*)&outp[o0 + 4] = make_float4(v[4], v[5], v[6], v[7]);
    }
  }
}

extern "C" void kernel_launch(void* const* d_in, const int* in_sizes, int n_in,
                              void* d_out, int out_size, void* d_ws, size_t ws_size,
                              hipStream_t stream) {
  const float* x  = (const float*)d_in[0];
  const int*   ei = (const int*)d_in[1];
  const int*   ec = (const int*)d_in[2];
  const float* W1 = (const float*)d_in[3];
  const float* b1 = (const float*)d_in[4];
  const float* W2 = (const float*)d_in[5];
  const float* b2 = (const float*)d_in[6];

  int nN = in_sizes[0] / 256;   // 100000
  int nE = in_sizes[2];         // 1600000
  const int* erow = ei;
  const int* ecol = ei + nE;
  int n64 = nN * 64;

  // ---- workspace layout (4B units) ----
  int* wsi = (int*)d_ws;
  int* mm   = wsi;                                   // 2
  int* gctr = wsi + 2;                               // 1
  unsigned long long* packed = (unsigned long long*)(wsi + 16);   // NT*nN u64
  int*   subbase = wsi + 16 + 2 * NT * nN;           // NT*nN
  int*   rowptr  = subbase + NT * nN;                // nN
  int*   cntv    = rowptr + nN;                      // nN
  float* dinv    = (float*)(cntv + nN);              // nN
  unsigned* srcw = (unsigned*)(dinv + nN);           // nE (u32 entries)
  unsigned short* xwh = (unsigned short*)(srcw + nE);  // [nN][64] bf16
  int*   rank    = (int*)xwh;                        // aliases xwh (dead at gemm1)
  float* h1      = (float*)(xwh + (size_t)n64);      // [nN,64] f32
  float* outp    = (float*)d_out;

  // ---- CSR build + normalization ----
  k_zero<<<(NT * nN + 255) / 256, 256, 0, stream>>>(packed, gctr, mm, NT * nN);
  k_hist<<<(nE + 255) / 256, 256, 0, stream>>>(ecol, ec, packed, rank, nE, nN);
  k_minmax<<<256, 256, 0, stream>>>(ec, nE, mm);
  k_base<<<(nN + 255) / 256, 256, 0, stream>>>(packed, mm, rowptr, cntv, dinv, subbase, gctr, nN);
  k_fill<<<(nE + 255) / 256, 256, 0, stream>>>(erow, ecol, ec, mm, subbase, rank, srcw, nE, nN);

  // ---- layer 1 ----
  k_gemm<256><<<(nN + 127) / 128, 256, 0, stream>>>(x, W1, xwh, nN);
  k_agg<false><<<(nN + 3) / 4, 256, 0, stream>>>(rowptr, cntv, srcw, dinv, xwh, b1, h1, nN);

  // ---- layer 2 ----
  k_gemm<64><<<(nN + 127) / 128, 256, 0, stream>>>(h1, W2, xwh, nN);
  k_agg<true><<<(nN + 3) / 4, 256, 0, stream>>>(rowptr, cntv, srcw, dinv, xwh, b2, outp, nN);
}